// Round 6
// baseline (107.810 us; speedup 1.0000x reference)
//
#include <hip/hip_runtime.h>

#define THREADS 256
#define FILL_BLOCKS 4096

// ---------------------------------------------------------------------------
// Block helpers (each leaves sdata reusable: trailing __syncthreads()).
// ---------------------------------------------------------------------------
__device__ __forceinline__ int blockReduceSum(int v, int* sdata) {
    int tid = threadIdx.x;
    sdata[tid] = v;
    __syncthreads();
    for (int off = THREADS >> 1; off > 0; off >>= 1) {
        if (tid < off) sdata[tid] += sdata[tid + off];
        __syncthreads();
    }
    int r = sdata[0];
    __syncthreads();
    return r;
}

__device__ __forceinline__ int blockScanIncl(int v, int* sdata) {
    int tid = threadIdx.x;
    sdata[tid] = v;
    __syncthreads();
    for (int off = 1; off < THREADS; off <<= 1) {
        int t = 0;
        if (tid >= off) t = sdata[tid - off];
        __syncthreads();
        if (tid >= off) sdata[tid] += t;
        __syncthreads();
    }
    int r = sdata[tid];
    __syncthreads();
    return r;
}

// ---------------------------------------------------------------------------
// Kernel 1: per-chunk count of segment starts (coalesced reads, no walks).
// ---------------------------------------------------------------------------
__global__ void k_count(const int* __restrict__ idx, int n, int E,
                        int* __restrict__ chunkCnt) {
    __shared__ int sdata[THREADS];
    int base = (blockIdx.x * THREADS + threadIdx.x) * E;
    int cnt = 0;
    for (int j = 0; j < E; ++j) {
        int p = base + j;
        if (p < n) cnt += (p == 0) || (idx[p - 1] != idx[p]);
    }
    int tot = blockReduceSum(cnt, sdata);
    if (threadIdx.x == 0) chunkCnt[blockIdx.x] = tot;
}

// ---------------------------------------------------------------------------
// Kernel 2: emit segOff (redundant inter-chunk prefix), nseg, sentinel.
// ---------------------------------------------------------------------------
__global__ void k_emit_starts(const int* __restrict__ idx, int n, int E, int NB,
                              const int* __restrict__ chunkCnt,
                              int* __restrict__ segOff,
                              int* __restrict__ nsegPtr) {
    __shared__ int sdata[THREADS];
    int tid = threadIdx.x, bid = blockIdx.x;

    int pv = 0;
    for (int i = tid; i < bid; i += THREADS) pv += chunkCnt[i];
    int prefix = blockReduceSum(pv, sdata);

    int base = (bid * THREADS + tid) * E;
    int cnt = 0;
    for (int j = 0; j < E; ++j) {
        int p = base + j;
        if (p < n) cnt += (p == 0) || (idx[p - 1] != idx[p]);
    }
    int incl = blockScanIncl(cnt, sdata);
    int off = prefix + incl - cnt;
    for (int j = 0; j < E; ++j) {
        int p = base + j;
        if (p < n && ((p == 0) || (idx[p - 1] != idx[p]))) segOff[off++] = p;
    }
    if (bid == NB - 1 && tid == THREADS - 1) {
        int nseg = prefix + incl;
        *nsegPtr = nseg;
        segOff[nseg] = n;                        // sentinel
    }
}

// ---------------------------------------------------------------------------
// Kernel 3 (merged tri_sums + emit_trioff): full-occupancy grid (NB blocks,
// 3/CU). Block b owns segments [s0, s1); it redundantly computes the C(c,2)
// prefix over [0, s0) with strided COALESCED reads of segOff (L2-hot,
// latency hidden by 12 waves/CU), then block-scans its own range and emits.
// ---------------------------------------------------------------------------
__global__ void k_trioff(const int* __restrict__ segOff,
                         const int* __restrict__ nsegPtr,
                         int* __restrict__ triOff) {
    __shared__ int sdata[THREADS];
    int nseg = *nsegPtr;
    int tid = threadIdx.x, bid = blockIdx.x;
    int segRange = (nseg + gridDim.x - 1) / gridDim.x;
    int s0 = bid * segRange; if (s0 > nseg) s0 = nseg;
    int s1 = s0 + segRange; if (s1 > nseg) s1 = nseg;

    // redundant prefix over [0, s0): strided, coalesced
    int pv = 0;
    for (int s = tid; s < s0; s += THREADS) {
        int c = segOff[s + 1] - segOff[s];
        pv += c * (c - 1) / 2;
    }
    int prefix = blockReduceSum(pv, sdata);

    // per-thread contiguous sub-range of [s0, s1)  (tE==1 for our sizes)
    int tE = (segRange + THREADS - 1) / THREADS;
    int a0 = s0 + tid * tE;
    int a1 = a0 + tE; if (a1 > s1) a1 = s1;
    int lsum = 0;
    for (int s = a0; s < a1; ++s) {
        int c = segOff[s + 1] - segOff[s];
        lsum += c * (c - 1) / 2;
    }
    int incl = blockScanIncl(lsum, sdata);
    int run = prefix + incl - lsum;
    for (int s = a0; s < a1; ++s) {
        int c = segOff[s + 1] - segOff[s];
        triOff[s] = run;
        run += c * (c - 1) / 2;
    }
}

// ---------------------------------------------------------------------------
// Kernel 4 (hot): wave-per-segment fill — verbatim round-2 (proven 86 µs).
// ---------------------------------------------------------------------------
__global__ void k_fill(const int* __restrict__ segOff,
                       const int* __restrict__ triOff,
                       const int* __restrict__ nsegPtr,
                       int* __restrict__ outI, int* __restrict__ outJ,
                       int* __restrict__ outK) {
    int nseg = *nsegPtr;
    int wid = blockIdx.x * (THREADS / 64) + (threadIdx.x >> 6);
    int lane = threadIdx.x & 63;
    int nW = gridDim.x * (THREADS / 64);
    for (int s = wid; s < nseg; s += nW) {
        int baseP = segOff[s];
        int c = segOff[s + 1] - baseP;
        int M = c * (c - 1) / 2;
        int t0 = triOff[s];
        for (int r = lane; r < M; r += 64) {
            int rr = M - 1 - r;
            int k = (int)floorf((sqrtf((float)(8 * rr + 1)) - 1.0f) * 0.5f);
            if (k < 0) k = 0;
            while ((k + 1) * (k + 2) / 2 <= rr) ++k;   // exact fix-up
            while (k * (k + 1) / 2 > rr) --k;
            int a = c - 2 - k;
            int b = c - 1 - (rr - k * (k + 1) / 2);
            int t = t0 + r;
            outI[t] = s;
            outJ[t] = baseP + a;
            outK[t] = baseP + b;
        }
    }
}

extern "C" void kernel_launch(void* const* d_in, const int* in_sizes, int n_in,
                              void* d_out, int out_size, void* d_ws, size_t ws_size,
                              hipStream_t stream) {
    const int* idx = (const int*)d_in[0];
    int n = in_sizes[0];
    int T = out_size / 3;
    int* out = (int*)d_out;
    int* ws = (int*)d_ws;

    // workspace layout (ints) — identical to round 2
    int* nsegPtr  = ws;                      // [1]
    int* chunkCnt = ws + 16;                 // [1024]
    int* segOff   = ws + 16 + 2048;          // [n+1] (sentinel at nseg)
    int* triOff   = segOff + (n + 1);        // [n]

    // per-thread element count so #chunks <= 1024
    int E = 8;
    while ((long long)(n + THREADS * E - 1) / (THREADS * E) > 1024) E <<= 1;
    int chunk = THREADS * E;
    int NB = (n + chunk - 1) / chunk;

    hipLaunchKernelGGL(k_count, dim3(NB), dim3(THREADS), 0, stream,
                       idx, n, E, chunkCnt);
    hipLaunchKernelGGL(k_emit_starts, dim3(NB), dim3(THREADS), 0, stream,
                       idx, n, E, NB, chunkCnt, segOff, nsegPtr);
    hipLaunchKernelGGL(k_trioff, dim3(NB), dim3(THREADS), 0, stream,
                       segOff, nsegPtr, triOff);
    hipLaunchKernelGGL(k_fill, dim3(FILL_BLOCKS), dim3(THREADS), 0, stream,
                       segOff, triOff, nsegPtr, out, out + T, out + 2 * T);
}

// Round 7
// 83.462 us; speedup vs baseline: 1.2917x; 1.2917x over previous
//
#include <hip/hip_runtime.h>

#define THREADS 256
#define EPT 8                      // elements per thread; chunk = 2048
#define FILL_BLOCKS 4096

// ---------------------------------------------------------------------------
// Block helpers (each leaves sdata reusable: trailing __syncthreads()).
// ---------------------------------------------------------------------------
__device__ __forceinline__ int blockReduceSum(int v, int* sdata) {
    int tid = threadIdx.x;
    sdata[tid] = v;
    __syncthreads();
    for (int off = THREADS >> 1; off > 0; off >>= 1) {
        if (tid < off) sdata[tid] += sdata[tid + off];
        __syncthreads();
    }
    int r = sdata[0];
    __syncthreads();
    return r;
}

__device__ __forceinline__ int blockScanIncl(int v, int* sdata) {
    int tid = threadIdx.x;
    sdata[tid] = v;
    __syncthreads();
    for (int off = 1; off < THREADS; off <<= 1) {
        int t = 0;
        if (tid >= off) t = sdata[tid - off];
        __syncthreads();
        if (tid >= off) sdata[tid] += t;
        __syncthreads();
    }
    int r = sdata[tid];
    __syncthreads();
    return r;
}

// exclusive max-scan (identity -1): result for tid = max over threads < tid
__device__ __forceinline__ int blockExclScanMax(int v, int* sdata) {
    int tid = threadIdx.x;
    sdata[tid] = v;
    __syncthreads();
    for (int off = 1; off < THREADS; off <<= 1) {
        int t = -1;
        if (tid >= off) t = sdata[tid - off];
        __syncthreads();
        if (tid >= off) sdata[tid] = max(sdata[tid], t);
        __syncthreads();
    }
    int r = (tid == 0) ? -1 : sdata[tid - 1];
    __syncthreads();
    return r;
}

// ---------------------------------------------------------------------------
// Find the last segment-start position <= B0-1 (requires B0 > 0).
// Vectorized backward probe: 256-element windows; terminates at p=0 worst
// case, typically 1 window (segments are ~32 long).
// ---------------------------------------------------------------------------
__device__ int findPrevStart(const int* __restrict__ idx, int B0,
                             int* sdata, int* s_found) {
    int tid = threadIdx.x;
    if (tid == 0) *s_found = -1;
    __syncthreads();
    int res = -1;
    for (int step = 0; res < 0; ++step) {
        int p = B0 - 1 - step * THREADS - tid;
        int cand = -1;
        if (p >= 0) {
            bool f = (p == 0) || (idx[p - 1] != idx[p]);
            if (f) cand = p;
        }
        sdata[tid] = cand;
        __syncthreads();
        for (int off = THREADS >> 1; off > 0; off >>= 1) {
            if (tid < off) sdata[tid] = max(sdata[tid], sdata[tid + off]);
            __syncthreads();
        }
        if (tid == 0 && sdata[0] >= 0) *s_found = sdata[0];
        __syncthreads();
        res = *s_found;
        __syncthreads();
    }
    return res;
}

// ---------------------------------------------------------------------------
// Kernel A: per-chunk (startCount, sum of local ranks q(p) = p - lastStart).
// Chunk tri-contribution uses only backward info => no cross-chunk hazards.
// ---------------------------------------------------------------------------
__global__ void k_chunkstats(const int* __restrict__ idx, int n,
                             int* __restrict__ chunkCnt,
                             int* __restrict__ chunkTriSum) {
    __shared__ int sdata[THREADS];
    __shared__ int s_tmp;
    int tid = threadIdx.x, bid = blockIdx.x;
    int B0 = bid * (THREADS * EPT);

    int prevStart = 0;
    if (bid > 0) prevStart = findPrevStart(idx, B0, sdata, &s_tmp);

    int base = B0 + tid * EPT;
    int cnt = 0, myLast = -1;
    for (int j = 0; j < EPT; ++j) {
        int p = base + j;
        if (p < n) {
            bool f = (p == 0) || (idx[p - 1] != idx[p]);
            if (f) { ++cnt; myLast = p; }
        }
    }
    int before = blockExclScanMax(myLast, sdata);
    int lastStart = max(prevStart, before);
    int sumq = 0;
    for (int j = 0; j < EPT; ++j) {
        int p = base + j;
        if (p < n) {
            if ((p == 0) || (idx[p - 1] != idx[p])) lastStart = p;
            sumq += p - lastStart;
        }
    }
    int c = blockReduceSum(cnt, sdata);
    int q = blockReduceSum(sumq, sdata);
    if (tid == 0) { chunkCnt[bid] = c; chunkTriSum[bid] = q; }
}

// ---------------------------------------------------------------------------
// Kernel B: chunk-level redundant prefix (<=1024 ints each — proven cheap),
// then emit segOff[ord]=p and triOff[ord]=global sum-of-q before p.
// ---------------------------------------------------------------------------
__global__ void k_emit(const int* __restrict__ idx, int n, int NB,
                       const int* __restrict__ chunkCnt,
                       const int* __restrict__ chunkTriSum,
                       int* __restrict__ segOff, int* __restrict__ triOff,
                       int* __restrict__ nsegPtr) {
    __shared__ int sdata[THREADS];
    __shared__ int s_tmp;
    int tid = threadIdx.x, bid = blockIdx.x;
    int B0 = bid * (THREADS * EPT);

    int prevStart = 0;
    if (bid > 0) prevStart = findPrevStart(idx, B0, sdata, &s_tmp);

    // chunk-level redundant prefix (cheap: <= NB ints per array)
    int pv = 0, tv = 0;
    for (int i = tid; i < bid; i += THREADS) {
        pv += chunkCnt[i];
        tv += chunkTriSum[i];
    }
    int segBase = blockReduceSum(pv, sdata);
    int triBase = blockReduceSum(tv, sdata);

    // pass 1: flags -> per-thread cnt + my last start
    int base = B0 + tid * EPT;
    int cnt = 0, myLast = -1;
    for (int j = 0; j < EPT; ++j) {
        int p = base + j;
        if (p < n) {
            bool f = (p == 0) || (idx[p - 1] != idx[p]);
            if (f) { ++cnt; myLast = p; }
        }
    }
    int before = blockExclScanMax(myLast, sdata);
    int lastStart0 = max(prevStart, before);

    // pass 2: per-thread sum of q
    int lastStart = lastStart0;
    int sumq = 0;
    for (int j = 0; j < EPT; ++j) {
        int p = base + j;
        if (p < n) {
            if ((p == 0) || (idx[p - 1] != idx[p])) lastStart = p;
            sumq += p - lastStart;
        }
    }

    int inclC = blockScanIncl(cnt, sdata);
    int inclQ = blockScanIncl(sumq, sdata);
    int ord  = segBase + inclC - cnt;
    int tcur = triBase + inclQ - sumq;

    // pass 3: emit
    lastStart = lastStart0;
    for (int j = 0; j < EPT; ++j) {
        int p = base + j;
        if (p < n) {
            bool f = (p == 0) || (idx[p - 1] != idx[p]);
            if (f) {
                segOff[ord] = p;
                triOff[ord] = tcur;        // q(p)=0 at a start
                ++ord;
                lastStart = p;
            }
            tcur += p - lastStart;
        }
    }
    if (bid == NB - 1 && tid == THREADS - 1) {
        int nseg = segBase + inclC;
        *nsegPtr = nseg;
        segOff[nseg] = n;                  // sentinel
    }
}

// ---------------------------------------------------------------------------
// Kernel C (hot): wave-per-segment fill — verbatim round-2 (proven 86 µs).
// ---------------------------------------------------------------------------
__global__ void k_fill(const int* __restrict__ segOff,
                       const int* __restrict__ triOff,
                       const int* __restrict__ nsegPtr,
                       int* __restrict__ outI, int* __restrict__ outJ,
                       int* __restrict__ outK) {
    int nseg = *nsegPtr;
    int wid = blockIdx.x * (THREADS / 64) + (threadIdx.x >> 6);
    int lane = threadIdx.x & 63;
    int nW = gridDim.x * (THREADS / 64);
    for (int s = wid; s < nseg; s += nW) {
        int baseP = segOff[s];
        int c = segOff[s + 1] - baseP;
        int M = c * (c - 1) / 2;
        int t0 = triOff[s];
        for (int r = lane; r < M; r += 64) {
            int rr = M - 1 - r;
            int k = (int)floorf((sqrtf((float)(8 * rr + 1)) - 1.0f) * 0.5f);
            if (k < 0) k = 0;
            while ((k + 1) * (k + 2) / 2 <= rr) ++k;   // exact fix-up
            while (k * (k + 1) / 2 > rr) --k;
            int a = c - 2 - k;
            int b = c - 1 - (rr - k * (k + 1) / 2);
            int t = t0 + r;
            outI[t] = s;
            outJ[t] = baseP + a;
            outK[t] = baseP + b;
        }
    }
}

extern "C" void kernel_launch(void* const* d_in, const int* in_sizes, int n_in,
                              void* d_out, int out_size, void* d_ws, size_t ws_size,
                              hipStream_t stream) {
    const int* idx = (const int*)d_in[0];
    int n = in_sizes[0];
    int T = out_size / 3;
    int* out = (int*)d_out;
    int* ws = (int*)d_ws;

    // workspace layout (ints)
    int* nsegPtr     = ws;                       // [1]
    int* chunkCnt    = ws + 16;                  // [8192]
    int* chunkTriSum = ws + 16 + 8192;           // [8192]
    int* segOff      = ws + 16 + 16384;          // [n+1] (sentinel at nseg)
    int* triOff      = segOff + (n + 1);         // [n]

    int chunk = THREADS * EPT;                   // 2048
    int NB = (n + chunk - 1) / chunk;            // 782 for n=1.6M

    hipLaunchKernelGGL(k_chunkstats, dim3(NB), dim3(THREADS), 0, stream,
                       idx, n, chunkCnt, chunkTriSum);
    hipLaunchKernelGGL(k_emit, dim3(NB), dim3(THREADS), 0, stream,
                       idx, n, NB, chunkCnt, chunkTriSum,
                       segOff, triOff, nsegPtr);
    hipLaunchKernelGGL(k_fill, dim3(FILL_BLOCKS), dim3(THREADS), 0, stream,
                       segOff, triOff, nsegPtr, out, out + T, out + 2 * T);
}

// Round 8
// 82.766 us; speedup vs baseline: 1.3026x; 1.0084x over previous
//
#include <hip/hip_runtime.h>

#define THREADS 256
#define EPT 8                      // elements per thread; chunk = 2048
#define FILL_BLOCKS 4096

// ---------------------------------------------------------------------------
// Block helpers (each leaves sdata reusable: trailing __syncthreads()).
// ---------------------------------------------------------------------------
__device__ __forceinline__ int blockReduceSum(int v, int* sdata) {
    int tid = threadIdx.x;
    sdata[tid] = v;
    __syncthreads();
    for (int off = THREADS >> 1; off > 0; off >>= 1) {
        if (tid < off) sdata[tid] += sdata[tid + off];
        __syncthreads();
    }
    int r = sdata[0];
    __syncthreads();
    return r;
}

__device__ __forceinline__ int blockScanIncl(int v, int* sdata) {
    int tid = threadIdx.x;
    sdata[tid] = v;
    __syncthreads();
    for (int off = 1; off < THREADS; off <<= 1) {
        int t = 0;
        if (tid >= off) t = sdata[tid - off];
        __syncthreads();
        if (tid >= off) sdata[tid] += t;
        __syncthreads();
    }
    int r = sdata[tid];
    __syncthreads();
    return r;
}

// exclusive max-scan (identity -1): result for tid = max over threads < tid
__device__ __forceinline__ int blockExclScanMax(int v, int* sdata) {
    int tid = threadIdx.x;
    sdata[tid] = v;
    __syncthreads();
    for (int off = 1; off < THREADS; off <<= 1) {
        int t = -1;
        if (tid >= off) t = sdata[tid - off];
        __syncthreads();
        if (tid >= off) sdata[tid] = max(sdata[tid], t);
        __syncthreads();
    }
    int r = (tid == 0) ? -1 : sdata[tid - 1];
    __syncthreads();
    return r;
}

// ---------------------------------------------------------------------------
// Find the last segment-start position <= B0-1 (requires B0 > 0).
// ---------------------------------------------------------------------------
__device__ int findPrevStart(const int* __restrict__ idx, int B0,
                             int* sdata, int* s_found) {
    int tid = threadIdx.x;
    if (tid == 0) *s_found = -1;
    __syncthreads();
    int res = -1;
    for (int step = 0; res < 0; ++step) {
        int p = B0 - 1 - step * THREADS - tid;
        int cand = -1;
        if (p >= 0) {
            bool f = (p == 0) || (idx[p - 1] != idx[p]);
            if (f) cand = p;
        }
        sdata[tid] = cand;
        __syncthreads();
        for (int off = THREADS >> 1; off > 0; off >>= 1) {
            if (tid < off) sdata[tid] = max(sdata[tid], sdata[tid + off]);
            __syncthreads();
        }
        if (tid == 0 && sdata[0] >= 0) *s_found = sdata[0];
        __syncthreads();
        res = *s_found;
        __syncthreads();
    }
    return res;
}

// ---------------------------------------------------------------------------
// Kernel A: per-chunk (startCount, sum of local ranks q(p) = p - lastStart).
// ---------------------------------------------------------------------------
__global__ void k_chunkstats(const int* __restrict__ idx, int n,
                             int* __restrict__ chunkCnt,
                             int* __restrict__ chunkTriSum) {
    __shared__ int sdata[THREADS];
    __shared__ int s_tmp;
    int tid = threadIdx.x, bid = blockIdx.x;
    int B0 = bid * (THREADS * EPT);

    int prevStart = 0;
    if (bid > 0) prevStart = findPrevStart(idx, B0, sdata, &s_tmp);

    int base = B0 + tid * EPT;
    int cnt = 0, myLast = -1;
    for (int j = 0; j < EPT; ++j) {
        int p = base + j;
        if (p < n) {
            bool f = (p == 0) || (idx[p - 1] != idx[p]);
            if (f) { ++cnt; myLast = p; }
        }
    }
    int before = blockExclScanMax(myLast, sdata);
    int lastStart = max(prevStart, before);
    int sumq = 0;
    for (int j = 0; j < EPT; ++j) {
        int p = base + j;
        if (p < n) {
            if ((p == 0) || (idx[p - 1] != idx[p])) lastStart = p;
            sumq += p - lastStart;
        }
    }
    int c = blockReduceSum(cnt, sdata);
    int q = blockReduceSum(sumq, sdata);
    if (tid == 0) { chunkCnt[bid] = c; chunkTriSum[bid] = q; }
}

// ---------------------------------------------------------------------------
// Kernel B: chunk-level redundant prefix, emit segOff + triOff + nseg.
// ---------------------------------------------------------------------------
__global__ void k_emit(const int* __restrict__ idx, int n, int NB,
                       const int* __restrict__ chunkCnt,
                       const int* __restrict__ chunkTriSum,
                       int* __restrict__ segOff, int* __restrict__ triOff,
                       int* __restrict__ nsegPtr) {
    __shared__ int sdata[THREADS];
    __shared__ int s_tmp;
    int tid = threadIdx.x, bid = blockIdx.x;
    int B0 = bid * (THREADS * EPT);

    int prevStart = 0;
    if (bid > 0) prevStart = findPrevStart(idx, B0, sdata, &s_tmp);

    int pv = 0, tv = 0;
    for (int i = tid; i < bid; i += THREADS) {
        pv += chunkCnt[i];
        tv += chunkTriSum[i];
    }
    int segBase = blockReduceSum(pv, sdata);
    int triBase = blockReduceSum(tv, sdata);

    int base = B0 + tid * EPT;
    int cnt = 0, myLast = -1;
    for (int j = 0; j < EPT; ++j) {
        int p = base + j;
        if (p < n) {
            bool f = (p == 0) || (idx[p - 1] != idx[p]);
            if (f) { ++cnt; myLast = p; }
        }
    }
    int before = blockExclScanMax(myLast, sdata);
    int lastStart0 = max(prevStart, before);

    int lastStart = lastStart0;
    int sumq = 0;
    for (int j = 0; j < EPT; ++j) {
        int p = base + j;
        if (p < n) {
            if ((p == 0) || (idx[p - 1] != idx[p])) lastStart = p;
            sumq += p - lastStart;
        }
    }

    int inclC = blockScanIncl(cnt, sdata);
    int inclQ = blockScanIncl(sumq, sdata);
    int ord  = segBase + inclC - cnt;
    int tcur = triBase + inclQ - sumq;

    lastStart = lastStart0;
    for (int j = 0; j < EPT; ++j) {
        int p = base + j;
        if (p < n) {
            bool f = (p == 0) || (idx[p - 1] != idx[p]);
            if (f) {
                segOff[ord] = p;
                triOff[ord] = tcur;
                ++ord;
                lastStart = p;
            }
            tcur += p - lastStart;
        }
    }
    if (bid == NB - 1 && tid == THREADS - 1) {
        int nseg = segBase + inclC;
        *nsegPtr = nseg;
        segOff[nseg] = n;                  // sentinel
    }
}

// ---------------------------------------------------------------------------
// Kernel C (hot): TRIPLE-BALANCED fill. Wave w owns output rows
// [T*w/nW, T*(w+1)/nW) — exact ±1 balance. One binary search over triOff
// (L2-hot) finds the starting segment; then walk segments, coalesced stores.
// ---------------------------------------------------------------------------
__global__ void k_fill(const int* __restrict__ segOff,
                       const int* __restrict__ triOff,
                       const int* __restrict__ nsegPtr, int T,
                       int* __restrict__ outI, int* __restrict__ outJ,
                       int* __restrict__ outK) {
    int nseg = *nsegPtr;
    int w = blockIdx.x * (THREADS / 64) + (threadIdx.x >> 6);
    int lane = threadIdx.x & 63;
    int nW = gridDim.x * (THREADS / 64);
    long long tlo = (long long)T * w / nW;
    long long thi = (long long)T * (w + 1) / nW;
    if (tlo >= thi) return;

    // largest s with triOff[s] <= tlo
    int lo = 0, hi = nseg - 1;
    while (lo < hi) {
        int mid = (lo + hi + 1) >> 1;
        if (triOff[mid] <= (int)tlo) lo = mid; else hi = mid - 1;
    }
    int s = lo;
    long long t = tlo;
    while (t < thi && s < nseg) {
        int baseP = segOff[s];
        int c = segOff[s + 1] - baseP;
        int M = c * (c - 1) / 2;
        int t0 = triOff[s];
        int rstart = (int)(t - t0);
        int rend = M;
        { long long cap = thi - t0; if (cap < (long long)rend) rend = (int)cap; }
        for (int r = rstart + lane; r < rend; r += 64) {
            int rr = M - 1 - r;
            int k = (int)floorf((sqrtf((float)(8 * rr + 1)) - 1.0f) * 0.5f);
            if (k < 0) k = 0;
            while ((k + 1) * (k + 2) / 2 <= rr) ++k;   // exact fix-up
            while (k * (k + 1) / 2 > rr) --k;
            int a = c - 2 - k;
            int b = c - 1 - (rr - k * (k + 1) / 2);
            int tt = t0 + r;
            outI[tt] = s;
            outJ[tt] = baseP + a;
            outK[tt] = baseP + b;
        }
        t = (long long)t0 + rend;
        ++s;
    }
}

extern "C" void kernel_launch(void* const* d_in, const int* in_sizes, int n_in,
                              void* d_out, int out_size, void* d_ws, size_t ws_size,
                              hipStream_t stream) {
    const int* idx = (const int*)d_in[0];
    int n = in_sizes[0];
    int T = out_size / 3;
    int* out = (int*)d_out;
    int* ws = (int*)d_ws;

    // workspace layout (ints)
    int* nsegPtr     = ws;                       // [1]
    int* chunkCnt    = ws + 16;                  // [8192]
    int* chunkTriSum = ws + 16 + 8192;           // [8192]
    int* segOff      = ws + 16 + 16384;          // [n+1] (sentinel at nseg)
    int* triOff      = segOff + (n + 1);         // [n]

    int chunk = THREADS * EPT;                   // 2048
    int NB = (n + chunk - 1) / chunk;            // 782 for n=1.6M

    hipLaunchKernelGGL(k_chunkstats, dim3(NB), dim3(THREADS), 0, stream,
                       idx, n, chunkCnt, chunkTriSum);
    hipLaunchKernelGGL(k_emit, dim3(NB), dim3(THREADS), 0, stream,
                       idx, n, NB, chunkCnt, chunkTriSum,
                       segOff, triOff, nsegPtr);
    hipLaunchKernelGGL(k_fill, dim3(FILL_BLOCKS), dim3(THREADS), 0, stream,
                       segOff, triOff, nsegPtr, T, out, out + T, out + 2 * T);
}

// Round 9
// 81.235 us; speedup vs baseline: 1.3271x; 1.0188x over previous
//
#include <hip/hip_runtime.h>

#define THREADS 256
#define EPT 8                      // elements per thread; chunk = 2048
#define FILL_BLOCKS 4096

// ---------------------------------------------------------------------------
// Block helpers (each leaves sdata reusable: trailing __syncthreads()).
// ---------------------------------------------------------------------------
__device__ __forceinline__ int blockReduceSum(int v, int* sdata) {
    int tid = threadIdx.x;
    sdata[tid] = v;
    __syncthreads();
    for (int off = THREADS >> 1; off > 0; off >>= 1) {
        if (tid < off) sdata[tid] += sdata[tid + off];
        __syncthreads();
    }
    int r = sdata[0];
    __syncthreads();
    return r;
}

__device__ __forceinline__ int blockScanIncl(int v, int* sdata) {
    int tid = threadIdx.x;
    sdata[tid] = v;
    __syncthreads();
    for (int off = 1; off < THREADS; off <<= 1) {
        int t = 0;
        if (tid >= off) t = sdata[tid - off];
        __syncthreads();
        if (tid >= off) sdata[tid] += t;
        __syncthreads();
    }
    int r = sdata[tid];
    __syncthreads();
    return r;
}

// exclusive max-scan (identity -1): result for tid = max over threads < tid
__device__ __forceinline__ int blockExclScanMax(int v, int* sdata) {
    int tid = threadIdx.x;
    sdata[tid] = v;
    __syncthreads();
    for (int off = 1; off < THREADS; off <<= 1) {
        int t = -1;
        if (tid >= off) t = sdata[tid - off];
        __syncthreads();
        if (tid >= off) sdata[tid] = max(sdata[tid], t);
        __syncthreads();
    }
    int r = (tid == 0) ? -1 : sdata[tid - 1];
    __syncthreads();
    return r;
}

// ---------------------------------------------------------------------------
// Find the last segment-start position <= B0-1 (requires B0 > 0).
// ---------------------------------------------------------------------------
__device__ int findPrevStart(const int* __restrict__ idx, int B0,
                             int* sdata, int* s_found) {
    int tid = threadIdx.x;
    if (tid == 0) *s_found = -1;
    __syncthreads();
    int res = -1;
    for (int step = 0; res < 0; ++step) {
        int p = B0 - 1 - step * THREADS - tid;
        int cand = -1;
        if (p >= 0) {
            bool f = (p == 0) || (idx[p - 1] != idx[p]);
            if (f) cand = p;
        }
        sdata[tid] = cand;
        __syncthreads();
        for (int off = THREADS >> 1; off > 0; off >>= 1) {
            if (tid < off) sdata[tid] = max(sdata[tid], sdata[tid + off]);
            __syncthreads();
        }
        if (tid == 0 && sdata[0] >= 0) *s_found = sdata[0];
        __syncthreads();
        res = *s_found;
        __syncthreads();
    }
    return res;
}

// ---------------------------------------------------------------------------
// Kernel A: per-chunk (startCount, sum of local ranks q(p) = p - lastStart).
// ---------------------------------------------------------------------------
__global__ void k_chunkstats(const int* __restrict__ idx, int n,
                             int* __restrict__ chunkCnt,
                             int* __restrict__ chunkTriSum) {
    __shared__ int sdata[THREADS];
    __shared__ int s_tmp;
    int tid = threadIdx.x, bid = blockIdx.x;
    int B0 = bid * (THREADS * EPT);

    int prevStart = 0;
    if (bid > 0) prevStart = findPrevStart(idx, B0, sdata, &s_tmp);

    int base = B0 + tid * EPT;
    int cnt = 0, myLast = -1;
    for (int j = 0; j < EPT; ++j) {
        int p = base + j;
        if (p < n) {
            bool f = (p == 0) || (idx[p - 1] != idx[p]);
            if (f) { ++cnt; myLast = p; }
        }
    }
    int before = blockExclScanMax(myLast, sdata);
    int lastStart = max(prevStart, before);
    int sumq = 0;
    for (int j = 0; j < EPT; ++j) {
        int p = base + j;
        if (p < n) {
            if ((p == 0) || (idx[p - 1] != idx[p])) lastStart = p;
            sumq += p - lastStart;
        }
    }
    int c = blockReduceSum(cnt, sdata);
    int q = blockReduceSum(sumq, sdata);
    if (tid == 0) { chunkCnt[bid] = c; chunkTriSum[bid] = q; }
}

// ---------------------------------------------------------------------------
// Kernel B: chunk-level redundant prefix, emit segOff + triOff + nseg.
// ---------------------------------------------------------------------------
__global__ void k_emit(const int* __restrict__ idx, int n, int NB,
                       const int* __restrict__ chunkCnt,
                       const int* __restrict__ chunkTriSum,
                       int* __restrict__ segOff, int* __restrict__ triOff,
                       int* __restrict__ nsegPtr) {
    __shared__ int sdata[THREADS];
    __shared__ int s_tmp;
    int tid = threadIdx.x, bid = blockIdx.x;
    int B0 = bid * (THREADS * EPT);

    int prevStart = 0;
    if (bid > 0) prevStart = findPrevStart(idx, B0, sdata, &s_tmp);

    int pv = 0, tv = 0;
    for (int i = tid; i < bid; i += THREADS) {
        pv += chunkCnt[i];
        tv += chunkTriSum[i];
    }
    int segBase = blockReduceSum(pv, sdata);
    int triBase = blockReduceSum(tv, sdata);

    int base = B0 + tid * EPT;
    int cnt = 0, myLast = -1;
    for (int j = 0; j < EPT; ++j) {
        int p = base + j;
        if (p < n) {
            bool f = (p == 0) || (idx[p - 1] != idx[p]);
            if (f) { ++cnt; myLast = p; }
        }
    }
    int before = blockExclScanMax(myLast, sdata);
    int lastStart0 = max(prevStart, before);

    int lastStart = lastStart0;
    int sumq = 0;
    for (int j = 0; j < EPT; ++j) {
        int p = base + j;
        if (p < n) {
            if ((p == 0) || (idx[p - 1] != idx[p])) lastStart = p;
            sumq += p - lastStart;
        }
    }

    int inclC = blockScanIncl(cnt, sdata);
    int inclQ = blockScanIncl(sumq, sdata);
    int ord  = segBase + inclC - cnt;
    int tcur = triBase + inclQ - sumq;

    lastStart = lastStart0;
    for (int j = 0; j < EPT; ++j) {
        int p = base + j;
        if (p < n) {
            bool f = (p == 0) || (idx[p - 1] != idx[p]);
            if (f) {
                segOff[ord] = p;
                triOff[ord] = tcur;
                ++ord;
                lastStart = p;
            }
            tcur += p - lastStart;
        }
    }
    if (bid == NB - 1 && tid == THREADS - 1) {
        int nseg = segBase + inclC;
        *nsegPtr = nseg;
        segOff[nseg] = n;                  // sentinel
    }
}

// ---------------------------------------------------------------------------
// Fill helpers.
// ---------------------------------------------------------------------------
// exact decode of backward rank rr for segment size c -> local (a,b), b>a
__device__ __forceinline__ void decodeRank(int rr, int c, int& a, int& b) {
    int k = (int)floorf((sqrtf((float)(8 * rr + 1)) - 1.0f) * 0.5f);
    if (k < 0) k = 0;
    while ((k + 1) * (k + 2) / 2 <= rr) ++k;   // exact fix-up
    while (k * (k + 1) / 2 > rr) --k;
    a = c - 2 - k;
    b = c - 1 - (rr - k * (k + 1) / 2);
}

__device__ __forceinline__ void emitOne(int r, int M, int c, int t0, int baseP,
                                        int s, int* __restrict__ outI,
                                        int* __restrict__ outJ,
                                        int* __restrict__ outK) {
    int a, b;
    decodeRank(M - 1 - r, c, a, b);
    int t = t0 + r;
    outI[t] = s;
    outJ[t] = baseP + a;
    outK[t] = baseP + b;
}

// store 4 consecutive ints at element offset t (t % 4 == 0) into stream P
// whose base has element phase PH (= stream_offset % 4) relative to 16B.
template <int PH>
__device__ __forceinline__ void storeQuad(int* __restrict__ P, int t, int4 v) {
    if constexpr (PH == 0) {
        *reinterpret_cast<int4*>(P + t) = v;
    } else if constexpr (PH == 2) {
        *reinterpret_cast<int2*>(P + t)     = make_int2(v.x, v.y);
        *reinterpret_cast<int2*>(P + t + 2) = make_int2(v.z, v.w);
    } else {
        P[t] = v.x;
        *reinterpret_cast<int2*>(P + t + 1) = make_int2(v.y, v.z);
        P[t + 3] = v.w;
    }
}

// ---------------------------------------------------------------------------
// Kernel C (hot): triple-balanced fill, QUAD inner loop. Each lane decodes
// one rank exactly, derives the next 3 via the lexicographic successor rule
// (b==c-1 ? (a+1,a+2) : (a,b+1)), stores 16B per stream (phase-templated).
// ---------------------------------------------------------------------------
template <int TMOD4>
__global__ void k_fill(const int* __restrict__ segOff,
                       const int* __restrict__ triOff,
                       const int* __restrict__ nsegPtr, int T,
                       int* __restrict__ outI, int* __restrict__ outJ,
                       int* __restrict__ outK) {
    constexpr int PHJ = TMOD4 & 3;          // element phase of outJ = T % 4
    constexpr int PHK = (2 * TMOD4) & 3;    // element phase of outK = 2T % 4
    int nseg = *nsegPtr;
    int w = blockIdx.x * (THREADS / 64) + (threadIdx.x >> 6);
    int lane = threadIdx.x & 63;
    int nW = gridDim.x * (THREADS / 64);
    long long tlo = (long long)T * w / nW;
    long long thi = (long long)T * (w + 1) / nW;
    if (tlo >= thi) return;

    // largest s with triOff[s] <= tlo
    int lo = 0, hi = nseg - 1;
    while (lo < hi) {
        int mid = (lo + hi + 1) >> 1;
        if (triOff[mid] <= (int)tlo) lo = mid; else hi = mid - 1;
    }
    int s = lo;
    long long t = tlo;
    while (t < thi && s < nseg) {
        int baseP = segOff[s];
        int c = segOff[s + 1] - baseP;
        int M = c * (c - 1) / 2;
        int t0 = triOff[s];
        int rstart = (int)(t - t0);
        int rend = M;
        { long long cap = thi - t0; if (cap < (long long)rend) rend = (int)cap; }

        // quad grid anchored at absolute t % 4 == 0 (t = t0 + r)
        int rA = rstart + ((4 - ((t0 + rstart) & 3)) & 3);
        if (rA > rend) rA = rend;
        int rB = rA + ((rend - rA) & ~3);

        // head (<=3) and tail (<=3) scalars, lane-strided
        for (int r = rstart + lane; r < rA; r += 64)
            emitOne(r, M, c, t0, baseP, s, outI, outJ, outK);
        for (int r = rB + lane; r < rend; r += 64)
            emitOne(r, M, c, t0, baseP, s, outI, outJ, outK);

        // quad interior
        int nq = (rB - rA) >> 2;
        for (int q = lane; q < nq; q += 64) {
            int r = rA + 4 * q;
            int a0, b0;
            decodeRank(M - 1 - r, c, a0, b0);
            int a1 = (b0 == c - 1) ? a0 + 1 : a0;
            int b1 = (b0 == c - 1) ? a0 + 2 : b0 + 1;
            int a2 = (b1 == c - 1) ? a1 + 1 : a1;
            int b2 = (b1 == c - 1) ? a1 + 2 : b1 + 1;
            int a3 = (b2 == c - 1) ? a2 + 1 : a2;
            int b3 = (b2 == c - 1) ? a2 + 2 : b2 + 1;
            int tt = t0 + r;                      // tt % 4 == 0
            storeQuad<0>(outI, tt, make_int4(s, s, s, s));
            storeQuad<PHJ>(outJ, tt,
                make_int4(baseP + a0, baseP + a1, baseP + a2, baseP + a3));
            storeQuad<PHK>(outK, tt,
                make_int4(baseP + b0, baseP + b1, baseP + b2, baseP + b3));
        }
        t = (long long)t0 + rend;
        ++s;
    }
}

extern "C" void kernel_launch(void* const* d_in, const int* in_sizes, int n_in,
                              void* d_out, int out_size, void* d_ws, size_t ws_size,
                              hipStream_t stream) {
    const int* idx = (const int*)d_in[0];
    int n = in_sizes[0];
    int T = out_size / 3;
    int* out = (int*)d_out;
    int* ws = (int*)d_ws;

    // workspace layout (ints)
    int* nsegPtr     = ws;                       // [1]
    int* chunkCnt    = ws + 16;                  // [8192]
    int* chunkTriSum = ws + 16 + 8192;           // [8192]
    int* segOff      = ws + 16 + 16384;          // [n+1] (sentinel at nseg)
    int* triOff      = segOff + (n + 1);         // [n]

    int chunk = THREADS * EPT;                   // 2048
    int NB = (n + chunk - 1) / chunk;            // 782 for n=1.6M

    hipLaunchKernelGGL(k_chunkstats, dim3(NB), dim3(THREADS), 0, stream,
                       idx, n, chunkCnt, chunkTriSum);
    hipLaunchKernelGGL(k_emit, dim3(NB), dim3(THREADS), 0, stream,
                       idx, n, NB, chunkCnt, chunkTriSum,
                       segOff, triOff, nsegPtr);
    int* outI = out;
    int* outJ = out + T;
    int* outK = out + 2 * T;
    switch (T & 3) {
        case 0:
            hipLaunchKernelGGL((k_fill<0>), dim3(FILL_BLOCKS), dim3(THREADS), 0,
                               stream, segOff, triOff, nsegPtr, T, outI, outJ, outK);
            break;
        case 1:
            hipLaunchKernelGGL((k_fill<1>), dim3(FILL_BLOCKS), dim3(THREADS), 0,
                               stream, segOff, triOff, nsegPtr, T, outI, outJ, outK);
            break;
        case 2:
            hipLaunchKernelGGL((k_fill<2>), dim3(FILL_BLOCKS), dim3(THREADS), 0,
                               stream, segOff, triOff, nsegPtr, T, outI, outJ, outK);
            break;
        default:
            hipLaunchKernelGGL((k_fill<3>), dim3(FILL_BLOCKS), dim3(THREADS), 0,
                               stream, segOff, triOff, nsegPtr, T, outI, outJ, outK);
            break;
    }
}